// Round 2
// baseline (8283.973 us; speedup 1.0000x reference)
//
#include <hip/hip_runtime.h>
#include <hip/hip_cooperative_groups.h>
#include <stdint.h>

namespace cg = cooperative_groups;

#define L 18
#define DIM (1 << L)
#define MKRY 64
#define NBLOCK 256
#define TPB 1024

// ---------------- threefry2x32 (JAX) ----------------
__device__ __forceinline__ uint32_t rotl32(uint32_t v, int r){ return (v<<r)|(v>>(32-r)); }

__device__ __forceinline__ void threefry2x32(uint32_t k0, uint32_t k1, uint32_t x0, uint32_t x1,
                                             uint32_t& o0, uint32_t& o1) {
  uint32_t k2 = k0 ^ k1 ^ 0x1BD11BDAu;
  x0 += k0; x1 += k1;
  x0+=x1; x1=rotl32(x1,13); x1^=x0;
  x0+=x1; x1=rotl32(x1,15); x1^=x0;
  x0+=x1; x1=rotl32(x1,26); x1^=x0;
  x0+=x1; x1=rotl32(x1,6);  x1^=x0;
  x0+=k1; x1+=k2+1u;
  x0+=x1; x1=rotl32(x1,17); x1^=x0;
  x0+=x1; x1=rotl32(x1,29); x1^=x0;
  x0+=x1; x1=rotl32(x1,16); x1^=x0;
  x0+=x1; x1=rotl32(x1,24); x1^=x0;
  x0+=k2; x1+=k0+2u;
  x0+=x1; x1=rotl32(x1,13); x1^=x0;
  x0+=x1; x1=rotl32(x1,15); x1^=x0;
  x0+=x1; x1=rotl32(x1,26); x1^=x0;
  x0+=x1; x1=rotl32(x1,6);  x1^=x0;
  x0+=k0; x1+=k1+3u;
  x0+=x1; x1=rotl32(x1,17); x1^=x0;
  x0+=x1; x1=rotl32(x1,29); x1^=x0;
  x0+=x1; x1=rotl32(x1,16); x1^=x0;
  x0+=x1; x1=rotl32(x1,24); x1^=x0;
  x0+=k1; x1+=k2+4u;
  x0+=x1; x1=rotl32(x1,13); x1^=x0;
  x0+=x1; x1=rotl32(x1,15); x1^=x0;
  x0+=x1; x1=rotl32(x1,26); x1^=x0;
  x0+=x1; x1=rotl32(x1,6);  x1^=x0;
  x0+=k2; x1+=k0+5u;
  o0=x0; o1=x1;
}

// XLA/chlo erf_inv f32 polynomial (Giles), contract-off
__device__ float jax_erfinv(float x){
  #pragma clang fp contract(off)
  float w = -log1pf(-x*x);
  float p;
  if (w < 5.0f) {
    w = w - 2.5f;
    p = 2.81022636e-08f;
    p = 3.43273939e-07f + p*w;
    p = -3.5233877e-06f + p*w;
    p = -4.39150654e-06f + p*w;
    p = 0.00021858087f + p*w;
    p = -0.00125372503f + p*w;
    p = -0.00417768164f + p*w;
    p = 0.246640727f + p*w;
    p = 1.50140941f + p*w;
  } else {
    w = sqrtf(w) - 3.0f;
    p = -0.000200214257f;
    p = 0.000100950558f + p*w;
    p = 0.00134934322f + p*w;
    p = -0.00367342844f + p*w;
    p = 0.00573950773f + p*w;
    p = -0.0076224613f + p*w;
    p = 0.00943887047f + p*w;
    p = 1.00167406f + p*w;
    p = 2.83297682f + p*w;
  }
  return p*x;
}

// Deterministic block reduce of two doubles (wave shfl tree + LDS combine).
// Result broadcast to all threads of the block.
__device__ __forceinline__ double2 blockReduce2(double a, double b){
  __shared__ double sa[16], sb[16], res[2];
  int lane = threadIdx.x & 63, wid = threadIdx.x >> 6;
  #pragma unroll
  for (int off=32; off; off>>=1){ a += __shfl_down(a,off,64); b += __shfl_down(b,off,64); }
  if (lane==0){ sa[wid]=a; sb[wid]=b; }
  __syncthreads();
  if (wid==0){
    double xa = (lane<16)? sa[lane] : 0.0;
    double xb = (lane<16)? sb[lane] : 0.0;
    #pragma unroll
    for (int off=8; off; off>>=1){ xa += __shfl_down(xa,off,64); xb += __shfl_down(xb,off,64); }
    if (lane==0){ res[0]=xa; res[1]=xb; }
  }
  __syncthreads();
  double2 r; r.x=res[0]; r.y=res[1];
  return r;
}

// Matrix-free H row for element s; numerics identical to the passed round-1 kernel.
__device__ __forceinline__ float matvec_elem(const float* __restrict__ v, int s, float vs,
                                             const float* __restrict__ scal){
  #pragma clang fp contract(off)
  float acc = 0.0f;
  // bonds i=0..16, site i = bit (17-i), site i+1 = bit (16-i)
  #pragma unroll
  for (int i=0;i<L-1;++i){
    int q = L-2-i;
    unsigned b2 = ((unsigned)s >> q) & 3u;
    if (b2==0u || b2==3u) { acc = acc + 0.25f*vs; }
    else if (b2==1u) { float t = -0.25f*vs; t = t + 0.5f*v[s ^ (3u<<q)]; acc = acc + t; }
    else             { float t = 0.5f*v[s ^ (3u<<q)]; t = t + (-0.25f)*vs; acc = acc + t; }
  }
  // fields i=0..17, site i = bit (17-i)
  #pragma unroll
  for (int i=0;i<L;++i){
    int p = L-1-i;
    unsigned mask = 1u<<p;
    float hx = scal[130+i], hz = scal[148+i];
    float t;
    if (s & mask) { t = hx*v[s^mask]; t = t + (-hz)*vs; }
    else          { t = hz*vs;        t = t + hx*v[s^mask]; }
    acc = acc + t;
  }
  return acc;
}

// scal layout (floats): [0..63] alphas | [64..127] betas |
// [130..147] hx | [148..165] hz | [192..447] U4 (64x4)

__global__ void __launch_bounds__(TPB, 4) k_pass1(const float* __restrict__ B0,
        const float* __restrict__ Bext, const float* __restrict__ phi,
        float* __restrict__ v0s, float* __restrict__ bufA, float* __restrict__ bufB,
        double* __restrict__ part, float* scal){
  cg::grid_group grid = cg::this_grid();
  const int tid = threadIdx.x, bid = blockIdx.x;
  const int s = bid*TPB + tid;

  // field coefficients (block 0), visible to all after the first grid sync
  if (bid==0 && tid < L){
    #pragma clang fp contract(off)
    float b0 = B0[0], be = Bext[0];
    double ph = (double)phi[tid];
    float Bx = b0*(float)sin(ph);
    float Bz = b0*(float)cos(ph);
    Bz = Bz + be;
    scal[130+tid] = 0.5f*Bx;
    scal[148+tid] = 0.5f*Bz;
  }

  // RNG (threefry, partitionable path: counter=(0, i), fold o0^o1)
  float n;
  {
    #pragma clang fp contract(off)
    uint32_t o0,o1; threefry2x32(0u, 42u, 0u, (uint32_t)s, o0, o1);
    uint32_t bits = o0 ^ o1;
    float f = __uint_as_float((bits >> 9) | 0x3f800000u) - 1.0f;
    const float lo = -0.99999994f;
    float u = f*2.0f;
    u = u + lo;
    u = fmaxf(lo, u);
    n = 1.41421354f * jax_erfinv(u);
  }
  double2 pr = blockReduce2((double)n*(double)n, 0.0);
  if (tid==0){ part[2*bid]=pr.x; part[2*bid+1]=pr.y; }
  grid.sync();

  float v_reg;
  {
    double pa=0.0, pb=0.0;
    if (tid<NBLOCK){ pa=part[2*tid]; pb=part[2*tid+1]; }
    double2 t = blockReduce2(pa, pb);
    float nrm = (float)sqrt(t.x);
    v_reg = __fdiv_rn(n, nrm);
    v0s[s] = v_reg;
  }
  float vp_reg = 0.0f, bp = 0.0f;
  grid.sync();

  const float* cur = v0s;
  for (int m=0; m<MKRY; ++m){
    float acc = matvec_elem(cur, s, v_reg, scal);
    double2 p2 = blockReduce2((double)v_reg*(double)acc, (double)acc*(double)acc);
    if (tid==0){ part[2*bid]=p2.x; part[2*bid+1]=p2.y; }
    grid.sync();                       // S1: partials visible

    double pa=0.0, pb=0.0;
    if (tid<NBLOCK){ pa=part[2*tid]; pb=part[2*tid+1]; }
    double2 t = blockReduce2(pa, pb);  // all blocks: identical deterministic reduce
    double alphaD = t.x, wwD = t.y;
    float alpha = (float)alphaD;
    double b2d = wwD - alphaD*alphaD - (double)bp*(double)bp;
    double betaD = sqrt(fmax(b2d, 0.0));
    float beta = (float)betaD;

    float x;
    {
      #pragma clang fp contract(off)
      x = acc - alpha*v_reg;
      x = x - bp*vp_reg;
    }
    float vn = __fdiv_rn(x, fmaxf(beta, 1e-12f));
    float* tgt = (m&1) ? bufB : bufA;
    tgt[s] = vn;
    if (s==0){ scal[m]=alpha; scal[64+m]=beta; }
    vp_reg = v_reg; v_reg = vn; bp = beta;
    grid.sync();                       // S2: v_next visible for next matvec
    cur = tgt;
  }
}

__global__ void __launch_bounds__(TPB, 4) k_pass2(const float* __restrict__ v0s,
        float* __restrict__ bufA, float* __restrict__ bufB,
        const float* __restrict__ scal, float* __restrict__ out){
  cg::grid_group grid = cg::this_grid();
  const int tid = threadIdx.x, bid = blockIdx.x;
  const int s = bid*TPB + tid;
  float v_reg = v0s[s], vp_reg = 0.0f;
  float o0=0.0f, o1=0.0f, o2=0.0f, o3=0.0f;
  const float* U = scal + 192;
  const float* cur = v0s;
  for (int m=0; m<MKRY; ++m){
    float acc = matvec_elem(cur, s, v_reg, scal);
    float alpha = scal[m];
    float bp = (m==0) ? 0.0f : scal[64+m-1];
    float beta = fmaxf(scal[64+m], 1e-12f);
    float x;
    {
      #pragma clang fp contract(off)
      x = acc - alpha*v_reg;
      x = x - bp*vp_reg;
    }
    float vn = __fdiv_rn(x, beta);
    {
      #pragma clang fp contract(off)
      o0 = o0 + v_reg*U[4*m+0];
      o1 = o1 + v_reg*U[4*m+1];
      o2 = o2 + v_reg*U[4*m+2];
      o3 = o3 + v_reg*U[4*m+3];
    }
    float* tgt = (m&1) ? bufB : bufA;
    tgt[s] = vn;
    vp_reg = v_reg; v_reg = vn;
    grid.sync();
    cur = tgt;
  }
  *(float4*)(out + 4 + 4*(size_t)s) = make_float4(o0,o1,o2,o3);
}

// tql2 (EISPACK) in f64, 64 threads
__global__ void k_eigh(float* __restrict__ scal, float* __restrict__ out){
  __shared__ double dd[64], ee[64], ss[64], cc[64];
  __shared__ double Z[64][65];
  __shared__ int m_sh, len_sh, jmin_sh;
  int t = threadIdx.x;
  dd[t] = (double)scal[t];
  ee[t] = (t<63)? (double)scal[64+t] : 0.0;
  for (int j=0;j<64;++j) Z[t][j] = (t==j)?1.0:0.0;
  __syncthreads();
  for (int l=0;l<64;++l){
    for (int iter=0; iter<80; ++iter){
      if (t==0){
        int m=l;
        while (m<63){
          double s2 = fabs(dd[m])+fabs(dd[m+1]);
          if (fabs(ee[m]) <= 2.220446049250313e-16 * s2) break;
          ++m;
        }
        m_sh = m;
      }
      __syncthreads();
      int m = m_sh;
      if (m==l) break;
      if (t==0){
        double g = (dd[l+1]-dd[l])/(2.0*ee[l]);
        double r = hypot(g, 1.0);
        g = dd[m]-dd[l] + ee[l]/(g + copysign(r,g));
        double s=1.0, c=1.0, p=0.0;
        int i = m-1;
        int stop = l;
        for (; i>=l; --i){
          double f = s*ee[i], b = c*ee[i];
          r = hypot(f,g);
          ee[i+1] = r;
          if (r==0.0){
            dd[i+1] -= p; ee[m]=0.0;
            stop = i+1;
            break;
          }
          s = f/r; c = g/r;
          g = dd[i+1]-p;
          double r2 = (dd[i]-g)*s + 2.0*c*b;
          p = s*r2;
          dd[i+1] = g+p;
          g = c*r2 - b;
          ss[i]=s; cc[i]=c;
        }
        if (i < l){
          dd[l] -= p; ee[l] = g; ee[m] = 0.0;
          stop = l;
        }
        len_sh = stop;
      }
      __syncthreads();
      int stop = len_sh;
      for (int i=m_sh-1; i>=stop; --i){
        double f = Z[t][i+1];
        Z[t][i+1] = ss[i]*Z[t][i] + cc[i]*f;
        Z[t][i]   = cc[i]*Z[t][i] - ss[i]*f;
      }
      __syncthreads();
    }
  }
  for (int k=0;k<63;++k){
    if (t==0){
      int jm=k;
      for (int j=k+1;j<64;++j) if (dd[j]<dd[jm]) jm=j;
      jmin_sh=jm;
    }
    __syncthreads();
    int jm=jmin_sh;
    if (jm!=k){
      if (t==0){ double tmp=dd[k]; dd[k]=dd[jm]; dd[jm]=tmp; }
      double tz=Z[t][k]; Z[t][k]=Z[t][jm]; Z[t][jm]=tz;
    }
    __syncthreads();
  }
  if (t<4) out[t] = (float)dd[t];
  for (int k=0;k<4;++k) scal[192 + t*4 + k] = (float)Z[t][k];
}

extern "C" void kernel_launch(void* const* d_in, const int* in_sizes, int n_in,
                              void* d_out, int out_size, void* d_ws, size_t ws_size,
                              hipStream_t stream){
  (void)in_sizes; (void)n_in; (void)ws_size; (void)out_size;
  const float* B0   = (const float*)d_in[0];
  const float* Bext = (const float*)d_in[1];
  const float* phi  = (const float*)d_in[2];
  float* out = (float*)d_out;

  float* v0s  = (float*)d_ws;
  float* bufA = v0s + DIM;
  float* bufB = bufA + DIM;
  double* part = (double*)(bufB + DIM);
  float* scal = (float*)(part + 2*NBLOCK);

  {
    void* args[] = { (void*)&B0, (void*)&Bext, (void*)&phi,
                     (void*)&v0s, (void*)&bufA, (void*)&bufB,
                     (void*)&part, (void*)&scal };
    hipLaunchCooperativeKernel((const void*)k_pass1, dim3(NBLOCK), dim3(TPB), args, 0, stream);
  }
  hipLaunchKernelGGL(k_eigh, dim3(1), dim3(64), 0, stream, scal, out);
  {
    void* args[] = { (void*)&v0s, (void*)&bufA, (void*)&bufB,
                     (void*)&scal, (void*)&out };
    hipLaunchCooperativeKernel((const void*)k_pass2, dim3(NBLOCK), dim3(TPB), args, 0, stream);
  }
}

// Round 4
// 3433.641 us; speedup vs baseline: 2.4126x; 2.4126x over previous
//
#include <hip/hip_runtime.h>
#include <stdint.h>

#define L 18
#define DIM (1 << L)
#define MKRY 64
#define NBLOCK 256
#define TPB 1024

// ---------------- threefry2x32 (JAX) ----------------
__device__ __forceinline__ uint32_t rotl32(uint32_t v, int r){ return (v<<r)|(v>>(32-r)); }

__device__ __forceinline__ void threefry2x32(uint32_t k0, uint32_t k1, uint32_t x0, uint32_t x1,
                                             uint32_t& o0, uint32_t& o1) {
  uint32_t k2 = k0 ^ k1 ^ 0x1BD11BDAu;
  x0 += k0; x1 += k1;
  x0+=x1; x1=rotl32(x1,13); x1^=x0;
  x0+=x1; x1=rotl32(x1,15); x1^=x0;
  x0+=x1; x1=rotl32(x1,26); x1^=x0;
  x0+=x1; x1=rotl32(x1,6);  x1^=x0;
  x0+=k1; x1+=k2+1u;
  x0+=x1; x1=rotl32(x1,17); x1^=x0;
  x0+=x1; x1=rotl32(x1,29); x1^=x0;
  x0+=x1; x1=rotl32(x1,16); x1^=x0;
  x0+=x1; x1=rotl32(x1,24); x1^=x0;
  x0+=k2; x1+=k0+2u;
  x0+=x1; x1=rotl32(x1,13); x1^=x0;
  x0+=x1; x1=rotl32(x1,15); x1^=x0;
  x0+=x1; x1=rotl32(x1,26); x1^=x0;
  x0+=x1; x1=rotl32(x1,6);  x1^=x0;
  x0+=k0; x1+=k1+3u;
  x0+=x1; x1=rotl32(x1,17); x1^=x0;
  x0+=x1; x1=rotl32(x1,29); x1^=x0;
  x0+=x1; x1=rotl32(x1,16); x1^=x0;
  x0+=x1; x1=rotl32(x1,24); x1^=x0;
  x0+=k1; x1+=k2+4u;
  x0+=x1; x1=rotl32(x1,13); x1^=x0;
  x0+=x1; x1=rotl32(x1,15); x1^=x0;
  x0+=x1; x1=rotl32(x1,26); x1^=x0;
  x0+=x1; x1=rotl32(x1,6);  x1^=x0;
  x0+=k2; x1+=k0+5u;
  o0=x0; o1=x1;
}

__device__ float jax_erfinv(float x){
  #pragma clang fp contract(off)
  float w = -log1pf(-x*x);
  float p;
  if (w < 5.0f) {
    w = w - 2.5f;
    p = 2.81022636e-08f;
    p = 3.43273939e-07f + p*w;
    p = -3.5233877e-06f + p*w;
    p = -4.39150654e-06f + p*w;
    p = 0.00021858087f + p*w;
    p = -0.00125372503f + p*w;
    p = -0.00417768164f + p*w;
    p = 0.246640727f + p*w;
    p = 1.50140941f + p*w;
  } else {
    w = sqrtf(w) - 3.0f;
    p = -0.000200214257f;
    p = 0.000100950558f + p*w;
    p = 0.00134934322f + p*w;
    p = -0.00367342844f + p*w;
    p = 0.00573950773f + p*w;
    p = -0.0076224613f + p*w;
    p = 0.00943887047f + p*w;
    p = 1.00167406f + p*w;
    p = 2.83297682f + p*w;
  }
  return p*x;
}

__device__ __forceinline__ float rng_val(unsigned i){
  #pragma clang fp contract(off)
  uint32_t o0,o1; threefry2x32(0u,42u,0u,i,o0,o1);
  uint32_t bits = o0 ^ o1;
  float f = __uint_as_float((bits >> 9) | 0x3f800000u) - 1.0f;
  const float lo = -0.99999994f;
  float u = f*2.0f;
  u = u + lo;
  u = fmaxf(lo, u);
  return 1.41421354f * jax_erfinv(u);
}

// Deterministic block reduce of two doubles; result broadcast to all threads.
__device__ __forceinline__ double2 blockReduce2(double a, double b){
  __shared__ double sa[16], sb[16], res[2];
  int lane = threadIdx.x & 63, wid = threadIdx.x >> 6;
  #pragma unroll
  for (int off=32; off; off>>=1){ a += __shfl_down(a,off,64); b += __shfl_down(b,off,64); }
  if (lane==0){ sa[wid]=a; sb[wid]=b; }
  __syncthreads();
  if (wid==0){
    double xa = (lane<16)? sa[lane] : 0.0;
    double xb = (lane<16)? sb[lane] : 0.0;
    #pragma unroll
    for (int off=8; off; off>>=1){ xa += __shfl_down(xa,off,64); xb += __shfl_down(xb,off,64); }
    if (lane==0){ res[0]=xa; res[1]=xb; }
  }
  __syncthreads();
  double2 r; r.x=res[0]; r.y=res[1];
  return r;
}

// ---------------- custom grid barrier (requires co-resident launch) ----------------
__device__ __forceinline__ void gbar(unsigned* bar, unsigned epoch){
  __syncthreads();
  if (threadIdx.x==0){
    unsigned prev = __hip_atomic_fetch_add(&bar[0], 1u, __ATOMIC_ACQ_REL, __HIP_MEMORY_SCOPE_AGENT);
    if (prev == NBLOCK-1u){
      __hip_atomic_store(&bar[0], 0u, __ATOMIC_RELAXED, __HIP_MEMORY_SCOPE_AGENT);
      __hip_atomic_fetch_add(&bar[1], 1u, __ATOMIC_RELEASE, __HIP_MEMORY_SCOPE_AGENT);
    } else {
      unsigned g; unsigned guard=0;
      do {
        g = __hip_atomic_load(&bar[1], __ATOMIC_RELAXED, __HIP_MEMORY_SCOPE_AGENT);
        if (g >= epoch) break;
        __builtin_amdgcn_s_sleep(1);
      } while (++guard < (1u<<20));
      (void)__hip_atomic_load(&bar[1], __ATOMIC_ACQUIRE, __HIP_MEMORY_SCOPE_AGENT);
    }
  }
  __syncthreads();
}

// ---------------- matrix-free H, neighbor access via functor ----------------
struct GetDir {
  const float* lds; const float* arr;
  __device__ __forceinline__ float operator()(unsigned nb, bool intra) const {
    return intra ? lds[nb & 1023u] : arr[nb];
  }
};
struct GetRec {  // reconstruct v_m[nb] = ((w-a*va)-bpp*vb)/bden  (bit-identical to owner's path)
  const float* lds; const float *wp, *va, *vb; float a_p, b_pp, bden;
  __device__ __forceinline__ float operator()(unsigned nb, bool intra) const {
    #pragma clang fp contract(off)
    if (intra) return lds[nb & 1023u];
    float x = wp[nb] - a_p*va[nb];
    x = x - b_pp*vb[nb];
    return __fdiv_rn(x, bden);
  }
};
struct GetRng {  // recompute v0[nb] = rng(nb)/nrm
  const float* lds; float nrm;
  __device__ __forceinline__ float operator()(unsigned nb, bool intra) const {
    if (intra) return lds[nb & 1023u];
    return __fdiv_rn(rng_val(nb), nrm);
  }
};

template<class G>
__device__ __forceinline__ float matvec_g(int s, float vs, const float* hxz, const G& g){
  #pragma clang fp contract(off)
  float acc = 0.0f;
  // bonds i=0..16, site i = bit (17-i), site i+1 = bit (16-i)
  #pragma unroll
  for (int i=0;i<L-1;++i){
    const int q = L-2-i;
    const unsigned msk = 3u<<q;
    const bool intra = (msk < 1024u);
    unsigned b2 = ((unsigned)s >> q) & 3u;
    if (b2==0u || b2==3u) { acc = acc + 0.25f*vs; }
    else if (b2==1u) { float t = -0.25f*vs; t = t + 0.5f*g((unsigned)s^msk, intra); acc = acc + t; }
    else             { float t = 0.5f*g((unsigned)s^msk, intra); t = t + (-0.25f)*vs; acc = acc + t; }
  }
  // fields i=0..17, site i = bit (17-i)
  #pragma unroll
  for (int i=0;i<L;++i){
    const int p = L-1-i;
    const unsigned msk = 1u<<p;
    const bool intra = (msk < 1024u);
    float hx = hxz[i], hz = hxz[18+i];
    float t;
    if ((unsigned)s & msk) { t = hx*g((unsigned)s^msk, intra); t = t + (-hz)*vs; }
    else                   { t = hz*vs; t = t + hx*g((unsigned)s^msk, intra); }
    acc = acc + t;
  }
  return acc;
}

// scal layout (floats): [0..63] alphas | [64..127] betas | [129] nrm |
// [130..147] hx | [148..165] hz | [192..447] U (64x4)

__global__ void k_init(unsigned* bar){ bar[0]=0u; bar[1]=0u; }

__global__ void __launch_bounds__(TPB) k_pass1(const float* __restrict__ B0,
        const float* __restrict__ Bext, const float* __restrict__ phi,
        float* __restrict__ vbase, int vmod, float* __restrict__ wring,
        double* __restrict__ part, float* scal, unsigned* bar){
  __shared__ float lds_v[TPB];
  __shared__ float lds_hxz[36];
  const int tid = threadIdx.x, bid = blockIdx.x;
  const int s = bid*TPB + tid;

  if (bid==0 && tid < L){
    #pragma clang fp contract(off)
    float b0 = B0[0], be = Bext[0];
    double ph = (double)phi[tid];
    float Bx = b0*(float)sin(ph);
    float Bz = b0*(float)cos(ph);
    Bz = Bz + be;
    scal[130+tid] = 0.5f*Bx;
    scal[148+tid] = 0.5f*Bz;
  }

  float n = rng_val((unsigned)s);
  {
    double2 pr = blockReduce2((double)n*(double)n, 0.0);
    double* pb = part + 512;  // RNG uses buf1
    if (tid==0){ pb[2*bid]=pr.x; pb[2*bid+1]=pr.y; }
  }
  gbar(bar, 1);

  if (tid < 36) lds_hxz[tid] = scal[130+tid];

  float v_reg;
  float nrm;
  {
    double pa=0.0, pbv=0.0;
    const double* pb = part + 512;
    if (tid<NBLOCK){ pa=pb[2*tid]; pbv=pb[2*tid+1]; }
    double2 t = blockReduce2(pa, pbv);
    nrm = (float)sqrt(t.x);
    v_reg = __fdiv_rn(n, nrm);
    vbase[s] = v_reg;          // slot 0 = v_0
    if (s==0) scal[129] = nrm;
    lds_v[tid] = v_reg;
  }
  float vp_reg = 0.0f, a_p = 0.0f, b_p = 0.0f, b_pp = 0.0f;
  gbar(bar, 2);

  for (int m=0; m<MKRY; ++m){
    __syncthreads();   // lds_v (and lds_hxz) ready
    float w;
    if (m==0){
      GetDir g{lds_v, vbase};
      w = matvec_g(s, v_reg, lds_hxz, g);
    } else {
      const float* va = vbase + (size_t)((m-1)%vmod)*DIM;
      const float* vb = vbase + (size_t)((m+vmod-2)%vmod)*DIM;  // m==1: dummy (x b_pp=0)
      const float* wp = wring + (size_t)((m-1)&1)*DIM;
      GetRec g{lds_v, wp, va, vb, a_p, b_pp, fmaxf(b_p, 1e-12f)};
      w = matvec_g(s, v_reg, lds_hxz, g);
    }
    wring[(size_t)(m&1)*DIM + s] = w;
    if (m>0) (vbase + (size_t)(m%vmod)*DIM)[s] = v_reg;

    double2 p2 = blockReduce2((double)v_reg*(double)w, (double)w*(double)w);
    double* pb = part + (size_t)(m&1)*512;
    if (tid==0){ pb[2*bid]=p2.x; pb[2*bid+1]=p2.y; }
    gbar(bar, 3+(unsigned)m);

    double xa=0.0, xb=0.0;
    if (tid<NBLOCK){ xa=pb[2*tid]; xb=pb[2*tid+1]; }
    double2 tt = blockReduce2(xa, xb);
    float alpha = (float)tt.x;
    double b2d = tt.y - tt.x*tt.x - (double)b_p*(double)b_p;
    float beta = (float)sqrt(fmax(b2d, 0.0));

    float x;
    {
      #pragma clang fp contract(off)
      x = w - alpha*v_reg;
      x = x - b_p*vp_reg;
    }
    float vn = __fdiv_rn(x, fmaxf(beta, 1e-12f));
    if (s==0){ scal[m]=alpha; scal[64+m]=beta; }
    b_pp=b_p; b_p=beta; a_p=alpha; vp_reg=v_reg; v_reg=vn;
    lds_v[tid]=vn;
  }
}

// big-ws: V fully stored, pass2 is a trivial accumulate
__global__ void __launch_bounds__(256) k_pass2s(const float* __restrict__ vbase,
        const float* __restrict__ scal, float* __restrict__ out){
  __shared__ float U[256];
  int tid = threadIdx.x;
  int s = blockIdx.x*256 + tid;
  U[tid] = scal[192+tid];
  __syncthreads();
  {
    #pragma clang fp contract(off)
    float o0=0.0f,o1=0.0f,o2=0.0f,o3=0.0f;
    for (int m=0;m<MKRY;++m){
      float vm = vbase[(size_t)m*DIM + s];
      o0 = o0 + vm*U[4*m+0];
      o1 = o1 + vm*U[4*m+1];
      o2 = o2 + vm*U[4*m+2];
      o3 = o3 + vm*U[4*m+3];
    }
    *(float4*)(out + 4 + 4*(size_t)s) = make_float4(o0,o1,o2,o3);
  }
}

// small-ws: cooperative pass2, direct gather (alphas/betas known)
__global__ void __launch_bounds__(TPB) k_pass2c(float* __restrict__ vbase, int vmod,
        const float* __restrict__ scal, float* __restrict__ out,
        unsigned* bar, int baseEpoch){
  __shared__ float lds_v[TPB];
  __shared__ float lds_hxz[36];
  __shared__ float lds_ab[384];  // [0..127] alphas/betas, [128..383] U
  const int tid = threadIdx.x, bid = blockIdx.x;
  const int s = bid*TPB + tid;
  if (tid < 36) lds_hxz[tid] = scal[130+tid];
  if (tid < 128) lds_ab[tid] = scal[tid];
  if (tid >= 128 && tid < 384) lds_ab[tid] = scal[192 + (tid-128)];
  float nrm = scal[129];
  float n = rng_val((unsigned)s);
  float v_reg = __fdiv_rn(n, nrm);
  float vp_reg = 0.0f;
  lds_v[tid] = v_reg;
  float o0=0.0f,o1=0.0f,o2=0.0f,o3=0.0f;
  for (int m=0;m<MKRY;++m){
    if (m>0) (vbase + (size_t)(m%vmod)*DIM)[s] = v_reg;
    gbar(bar, (unsigned)(baseEpoch+1+m));
    float w;
    if (m==0){
      GetRng g{lds_v, nrm};
      w = matvec_g(s, v_reg, lds_hxz, g);
    } else {
      GetDir g{lds_v, vbase + (size_t)(m%vmod)*DIM};
      w = matvec_g(s, v_reg, lds_hxz, g);
    }
    float alpha = lds_ab[m];
    float bp = (m==0)? 0.0f : lds_ab[64+m-1];
    float beta = fmaxf(lds_ab[64+m], 1e-12f);
    float x;
    {
      #pragma clang fp contract(off)
      x = w - alpha*v_reg;
      x = x - bp*vp_reg;
    }
    float vn = __fdiv_rn(x, beta);
    {
      #pragma clang fp contract(off)
      o0 = o0 + v_reg*lds_ab[128+4*m+0];
      o1 = o1 + v_reg*lds_ab[128+4*m+1];
      o2 = o2 + v_reg*lds_ab[128+4*m+2];
      o3 = o3 + v_reg*lds_ab[128+4*m+3];
    }
    vp_reg = v_reg; v_reg = vn;
    __syncthreads();
    lds_v[tid] = vn;
  }
  *(float4*)(out + 4 + 4*(size_t)s) = make_float4(o0,o1,o2,o3);
}

// tql2 (EISPACK) f64; all 64 lanes redundantly run the scalar chain in registers,
// each applies rotations to its own Z row fused in-loop. Same FP op order as before.
__global__ void k_eigh(float* __restrict__ scal, float* __restrict__ out){
  __shared__ double dd[64], ee[64];
  __shared__ double Z[64][65];
  int t = threadIdx.x;
  dd[t] = (double)scal[t];
  ee[t] = (t<63)? (double)scal[64+t] : 0.0;
  for (int j=0;j<64;++j) Z[t][j] = (t==j)?1.0:0.0;
  __syncthreads();
  for (int l=0;l<64;++l){
    for (int iter=0; iter<80; ++iter){
      int m=l;
      while (m<63){
        double s2 = fabs(dd[m])+fabs(dd[m+1]);
        if (fabs(ee[m]) <= 2.220446049250313e-16 * s2) break;
        ++m;
      }
      if (m==l) break;
      double g = (dd[l+1]-dd[l])/(2.0*ee[l]);
      double r = hypot(g, 1.0);
      g = dd[m]-dd[l] + ee[l]/(g + copysign(r,g));
      double s=1.0, c=1.0, p=0.0;
      int i = m-1;
      bool brk=false;
      for (; i>=l; --i){
        double f = s*ee[i], b = c*ee[i];
        r = hypot(f,g);
        if (t==0) ee[i+1] = r;
        if (r==0.0){
          if (t==0){ dd[i+1] -= p; ee[m]=0.0; }
          brk=true;
          break;
        }
        s = f/r; c = g/r;
        g = dd[i+1]-p;
        double r2 = (dd[i]-g)*s + 2.0*c*b;
        p = s*r2;
        if (t==0) dd[i+1] = g+p;
        g = c*r2 - b;
        // apply rotation i to own row
        double zf = Z[t][i+1], zi = Z[t][i];
        Z[t][i+1] = s*zi + c*zf;
        Z[t][i]   = c*zi - s*zf;
      }
      if (!brk && t==0){ dd[l] -= p; ee[l] = g; ee[m] = 0.0; }
      __syncthreads();
    }
  }
  // ascending selection sort, permute columns
  for (int k=0;k<63;++k){
    int jm=k;
    for (int j=k+1;j<64;++j) if (dd[j]<dd[jm]) jm=j;
    __syncthreads();
    if (jm!=k){
      if (t==0){ double tmp=dd[k]; dd[k]=dd[jm]; dd[jm]=tmp; }
      double tz=Z[t][k]; Z[t][k]=Z[t][jm]; Z[t][jm]=tz;
    }
    __syncthreads();
  }
  if (t<4) out[t] = (float)dd[t];
  for (int k=0;k<4;++k) scal[192 + t*4 + k] = (float)Z[t][k];
}

extern "C" void kernel_launch(void* const* d_in, const int* in_sizes, int n_in,
                              void* d_out, int out_size, void* d_ws, size_t ws_size,
                              hipStream_t stream){
  (void)in_sizes; (void)n_in; (void)out_size;
  const float* B0   = (const float*)d_in[0];
  const float* Bext = (const float*)d_in[1];
  const float* phi  = (const float*)d_in[2];
  float* out = (float*)d_out;

  size_t need_big = ((size_t)(MKRY+2)*DIM)*4 + 1024*8 + 512*4 + 256;
  int vmod; bool big;
  if (ws_size >= need_big + (1u<<20)) { vmod = MKRY; big = true; }
  else                               { vmod = 3;    big = false; }

  float* vbase = (float*)d_ws;
  float* wring = vbase + (size_t)vmod*DIM;
  double* part = (double*)(wring + 2*(size_t)DIM);
  float* scal  = (float*)(part + 1024);
  unsigned* bar = (unsigned*)(scal + 512);

  hipLaunchKernelGGL(k_init, dim3(1), dim3(1), 0, stream, bar);
  {
    void* args[] = { (void*)&B0, (void*)&Bext, (void*)&phi,
                     (void*)&vbase, (void*)&vmod, (void*)&wring,
                     (void*)&part, (void*)&scal, (void*)&bar };
    (void)hipLaunchCooperativeKernel((const void*)k_pass1, dim3(NBLOCK), dim3(TPB), args, 0, stream);
  }
  hipLaunchKernelGGL(k_eigh, dim3(1), dim3(64), 0, stream, scal, out);
  if (big){
    hipLaunchKernelGGL(k_pass2s, dim3(DIM/256), dim3(256), 0, stream, vbase, scal, out);
  } else {
    int baseEpoch = 66;
    void* args[] = { (void*)&vbase, (void*)&vmod, (void*)&scal,
                     (void*)&out, (void*)&bar, (void*)&baseEpoch };
    (void)hipLaunchCooperativeKernel((const void*)k_pass2c, dim3(NBLOCK), dim3(TPB), args, 0, stream);
  }
}

// Round 5
// 3331.050 us; speedup vs baseline: 2.4869x; 1.0308x over previous
//
#include <hip/hip_runtime.h>
#include <stdint.h>

#define L 18
#define DIM (1 << L)
#define MKRY 64
#define NBLOCK 256
#define TPB 1024

// ---------------- threefry2x32 (JAX) ----------------
__device__ __forceinline__ uint32_t rotl32(uint32_t v, int r){ return (v<<r)|(v>>(32-r)); }

__device__ __forceinline__ void threefry2x32(uint32_t k0, uint32_t k1, uint32_t x0, uint32_t x1,
                                             uint32_t& o0, uint32_t& o1) {
  uint32_t k2 = k0 ^ k1 ^ 0x1BD11BDAu;
  x0 += k0; x1 += k1;
  x0+=x1; x1=rotl32(x1,13); x1^=x0;
  x0+=x1; x1=rotl32(x1,15); x1^=x0;
  x0+=x1; x1=rotl32(x1,26); x1^=x0;
  x0+=x1; x1=rotl32(x1,6);  x1^=x0;
  x0+=k1; x1+=k2+1u;
  x0+=x1; x1=rotl32(x1,17); x1^=x0;
  x0+=x1; x1=rotl32(x1,29); x1^=x0;
  x0+=x1; x1=rotl32(x1,16); x1^=x0;
  x0+=x1; x1=rotl32(x1,24); x1^=x0;
  x0+=k2; x1+=k0+2u;
  x0+=x1; x1=rotl32(x1,13); x1^=x0;
  x0+=x1; x1=rotl32(x1,15); x1^=x0;
  x0+=x1; x1=rotl32(x1,26); x1^=x0;
  x0+=x1; x1=rotl32(x1,6);  x1^=x0;
  x0+=k0; x1+=k1+3u;
  x0+=x1; x1=rotl32(x1,17); x1^=x0;
  x0+=x1; x1=rotl32(x1,29); x1^=x0;
  x0+=x1; x1=rotl32(x1,16); x1^=x0;
  x0+=x1; x1=rotl32(x1,24); x1^=x0;
  x0+=k1; x1+=k2+4u;
  x0+=x1; x1=rotl32(x1,13); x1^=x0;
  x0+=x1; x1=rotl32(x1,15); x1^=x0;
  x0+=x1; x1=rotl32(x1,26); x1^=x0;
  x0+=x1; x1=rotl32(x1,6);  x1^=x0;
  x0+=k2; x1+=k0+5u;
  o0=x0; o1=x1;
}

__device__ float jax_erfinv(float x){
  #pragma clang fp contract(off)
  float w = -log1pf(-x*x);
  float p;
  if (w < 5.0f) {
    w = w - 2.5f;
    p = 2.81022636e-08f;
    p = 3.43273939e-07f + p*w;
    p = -3.5233877e-06f + p*w;
    p = -4.39150654e-06f + p*w;
    p = 0.00021858087f + p*w;
    p = -0.00125372503f + p*w;
    p = -0.00417768164f + p*w;
    p = 0.246640727f + p*w;
    p = 1.50140941f + p*w;
  } else {
    w = sqrtf(w) - 3.0f;
    p = -0.000200214257f;
    p = 0.000100950558f + p*w;
    p = 0.00134934322f + p*w;
    p = -0.00367342844f + p*w;
    p = 0.00573950773f + p*w;
    p = -0.0076224613f + p*w;
    p = 0.00943887047f + p*w;
    p = 1.00167406f + p*w;
    p = 2.83297682f + p*w;
  }
  return p*x;
}

__device__ __forceinline__ float rng_val(unsigned i){
  #pragma clang fp contract(off)
  uint32_t o0,o1; threefry2x32(0u,42u,0u,i,o0,o1);
  uint32_t bits = o0 ^ o1;
  float f = __uint_as_float((bits >> 9) | 0x3f800000u) - 1.0f;
  const float lo = -0.99999994f;
  float u = f*2.0f;
  u = u + lo;
  u = fmaxf(lo, u);
  return 1.41421354f * jax_erfinv(u);
}

// Deterministic block reduce of two doubles; result broadcast to all threads.
__device__ __forceinline__ double2 blockReduce2(double a, double b){
  __shared__ double sa[16], sb[16], res[2];
  int lane = threadIdx.x & 63, wid = threadIdx.x >> 6;
  #pragma unroll
  for (int off=32; off; off>>=1){ a += __shfl_down(a,off,64); b += __shfl_down(b,off,64); }
  if (lane==0){ sa[wid]=a; sb[wid]=b; }
  __syncthreads();
  if (wid==0){
    double xa = (lane<16)? sa[lane] : 0.0;
    double xb = (lane<16)? sb[lane] : 0.0;
    #pragma unroll
    for (int off=8; off; off>>=1){ xa += __shfl_down(xa,off,64); xb += __shfl_down(xb,off,64); }
    if (lane==0){ res[0]=xa; res[1]=xb; }
  }
  __syncthreads();
  double2 r; r.x=res[0]; r.y=res[1];
  return r;
}

// ---------------- custom grid barrier (requires co-resident launch) ----------------
__device__ __forceinline__ void gbar(unsigned* bar, unsigned epoch){
  __syncthreads();
  if (threadIdx.x==0){
    unsigned prev = __hip_atomic_fetch_add(&bar[0], 1u, __ATOMIC_ACQ_REL, __HIP_MEMORY_SCOPE_AGENT);
    if (prev == NBLOCK-1u){
      __hip_atomic_store(&bar[0], 0u, __ATOMIC_RELAXED, __HIP_MEMORY_SCOPE_AGENT);
      __hip_atomic_fetch_add(&bar[1], 1u, __ATOMIC_RELEASE, __HIP_MEMORY_SCOPE_AGENT);
    } else {
      unsigned g; unsigned guard=0;
      do {
        g = __hip_atomic_load(&bar[1], __ATOMIC_RELAXED, __HIP_MEMORY_SCOPE_AGENT);
        if (g >= epoch) break;
        __builtin_amdgcn_s_sleep(1);
      } while (++guard < (1u<<20));
      (void)__hip_atomic_load(&bar[1], __ATOMIC_ACQUIRE, __HIP_MEMORY_SCOPE_AGENT);
    }
  }
  __syncthreads();
}

// ---------------- matrix-free H, neighbor access via functor ----------------
struct GetDir {
  const float* lds; const float* arr;
  __device__ __forceinline__ float operator()(unsigned nb, bool intra) const {
    return intra ? lds[nb & 1023u] : arr[nb];
  }
};
struct GetRec {  // reconstruct v_m[nb] = ((w-a*va)-bpp*vb)/bden  (bit-identical to owner's path)
  const float* lds; const float *wp, *va, *vb; float a_p, b_pp, bden;
  __device__ __forceinline__ float operator()(unsigned nb, bool intra) const {
    #pragma clang fp contract(off)
    if (intra) return lds[nb & 1023u];
    float x = wp[nb] - a_p*va[nb];
    x = x - b_pp*vb[nb];
    return __fdiv_rn(x, bden);
  }
};
struct GetRng {  // recompute v0[nb] = rng(nb)/nrm
  const float* lds; float nrm;
  __device__ __forceinline__ float operator()(unsigned nb, bool intra) const {
    if (intra) return lds[nb & 1023u];
    return __fdiv_rn(rng_val(nb), nrm);
  }
};

template<class G>
__device__ __forceinline__ float matvec_g(int s, float vs, const float* hxz, const G& g){
  #pragma clang fp contract(off)
  float acc = 0.0f;
  // bonds i=0..16, site i = bit (17-i), site i+1 = bit (16-i)
  #pragma unroll
  for (int i=0;i<L-1;++i){
    const int q = L-2-i;
    const unsigned msk = 3u<<q;
    const bool intra = (msk < 1024u);
    unsigned b2 = ((unsigned)s >> q) & 3u;
    if (b2==0u || b2==3u) { acc = acc + 0.25f*vs; }
    else if (b2==1u) { float t = -0.25f*vs; t = t + 0.5f*g((unsigned)s^msk, intra); acc = acc + t; }
    else             { float t = 0.5f*g((unsigned)s^msk, intra); t = t + (-0.25f)*vs; acc = acc + t; }
  }
  // fields i=0..17, site i = bit (17-i)
  #pragma unroll
  for (int i=0;i<L;++i){
    const int p = L-1-i;
    const unsigned msk = 1u<<p;
    const bool intra = (msk < 1024u);
    float hx = hxz[i], hz = hxz[18+i];
    float t;
    if ((unsigned)s & msk) { t = hx*g((unsigned)s^msk, intra); t = t + (-hz)*vs; }
    else                   { t = hz*vs; t = t + hx*g((unsigned)s^msk, intra); }
    acc = acc + t;
  }
  return acc;
}

// scal layout (floats): [0..63] alphas | [64..127] betas | [129] nrm |
// [130..147] hx | [148..165] hz | [192..447] U (64x4)

__global__ void k_init(unsigned* bar){ bar[0]=0u; bar[1]=0u; }

__global__ void __launch_bounds__(TPB) k_pass1(const float* __restrict__ B0,
        const float* __restrict__ Bext, const float* __restrict__ phi,
        float* __restrict__ vbase, int vmod, float* __restrict__ wring,
        double* __restrict__ part, float* scal, unsigned* bar){
  __shared__ float lds_v[TPB];
  __shared__ float lds_hxz[36];
  const int tid = threadIdx.x, bid = blockIdx.x;
  const int s = bid*TPB + tid;

  if (bid==0 && tid < L){
    #pragma clang fp contract(off)
    float b0 = B0[0], be = Bext[0];
    double ph = (double)phi[tid];
    float Bx = b0*(float)sin(ph);
    float Bz = b0*(float)cos(ph);
    Bz = Bz + be;
    scal[130+tid] = 0.5f*Bx;
    scal[148+tid] = 0.5f*Bz;
  }

  float n = rng_val((unsigned)s);
  {
    double2 pr = blockReduce2((double)n*(double)n, 0.0);
    double* pb = part + 512;  // RNG uses buf1
    if (tid==0){ pb[2*bid]=pr.x; pb[2*bid+1]=pr.y; }
  }
  gbar(bar, 1);

  if (tid < 36) lds_hxz[tid] = scal[130+tid];

  float v_reg;
  float nrm;
  {
    double pa=0.0, pbv=0.0;
    const double* pb = part + 512;
    if (tid<NBLOCK){ pa=pb[2*tid]; pbv=pb[2*tid+1]; }
    double2 t = blockReduce2(pa, pbv);
    nrm = (float)sqrt(t.x);
    v_reg = __fdiv_rn(n, nrm);
    vbase[s] = v_reg;          // slot 0 = v_0
    if (s==0) scal[129] = nrm;
    lds_v[tid] = v_reg;
  }
  float vp_reg = 0.0f, a_p = 0.0f, b_p = 0.0f, b_pp = 0.0f;
  gbar(bar, 2);

  for (int m=0; m<MKRY; ++m){
    __syncthreads();   // lds_v (and lds_hxz) ready
    float w;
    if (m==0){
      GetDir g{lds_v, vbase};
      w = matvec_g(s, v_reg, lds_hxz, g);
    } else {
      const float* va = vbase + (size_t)((m-1)%vmod)*DIM;
      const float* vb = vbase + (size_t)((m+vmod-2)%vmod)*DIM;  // m==1: dummy (x b_pp=0)
      const float* wp = wring + (size_t)((m-1)&1)*DIM;
      GetRec g{lds_v, wp, va, vb, a_p, b_pp, fmaxf(b_p, 1e-12f)};
      w = matvec_g(s, v_reg, lds_hxz, g);
    }
    wring[(size_t)(m&1)*DIM + s] = w;
    if (m>0) (vbase + (size_t)(m%vmod)*DIM)[s] = v_reg;

    double2 p2 = blockReduce2((double)v_reg*(double)w, (double)w*(double)w);
    double* pb = part + (size_t)(m&1)*512;
    if (tid==0){ pb[2*bid]=p2.x; pb[2*bid+1]=p2.y; }
    gbar(bar, 3+(unsigned)m);

    double xa=0.0, xb=0.0;
    if (tid<NBLOCK){ xa=pb[2*tid]; xb=pb[2*tid+1]; }
    double2 tt = blockReduce2(xa, xb);
    float alpha = (float)tt.x;
    double b2d = tt.y - tt.x*tt.x - (double)b_p*(double)b_p;
    float beta = (float)sqrt(fmax(b2d, 0.0));

    float x;
    {
      #pragma clang fp contract(off)
      x = w - alpha*v_reg;
      x = x - b_p*vp_reg;
    }
    float vn = __fdiv_rn(x, fmaxf(beta, 1e-12f));
    if (s==0){ scal[m]=alpha; scal[64+m]=beta; }
    b_pp=b_p; b_p=beta; a_p=alpha; vp_reg=v_reg; v_reg=vn;
    lds_v[tid]=vn;
  }
}

// big-ws: V fully stored, pass2 is a trivial accumulate
__global__ void __launch_bounds__(256) k_pass2s(const float* __restrict__ vbase,
        const float* __restrict__ scal, float* __restrict__ out){
  __shared__ float U[256];
  int tid = threadIdx.x;
  int s = blockIdx.x*256 + tid;
  U[tid] = scal[192+tid];
  __syncthreads();
  {
    #pragma clang fp contract(off)
    float o0=0.0f,o1=0.0f,o2=0.0f,o3=0.0f;
    for (int m=0;m<MKRY;++m){
      float vm = vbase[(size_t)m*DIM + s];
      o0 = o0 + vm*U[4*m+0];
      o1 = o1 + vm*U[4*m+1];
      o2 = o2 + vm*U[4*m+2];
      o3 = o3 + vm*U[4*m+3];
    }
    *(float4*)(out + 4 + 4*(size_t)s) = make_float4(o0,o1,o2,o3);
  }
}

// small-ws: cooperative pass2, direct gather (alphas/betas known)
__global__ void __launch_bounds__(TPB) k_pass2c(float* __restrict__ vbase, int vmod,
        const float* __restrict__ scal, float* __restrict__ out,
        unsigned* bar, int baseEpoch){
  __shared__ float lds_v[TPB];
  __shared__ float lds_hxz[36];
  __shared__ float lds_ab[384];  // [0..127] alphas/betas, [128..383] U
  const int tid = threadIdx.x, bid = blockIdx.x;
  const int s = bid*TPB + tid;
  if (tid < 36) lds_hxz[tid] = scal[130+tid];
  if (tid < 128) lds_ab[tid] = scal[tid];
  if (tid >= 128 && tid < 384) lds_ab[tid] = scal[192 + (tid-128)];
  float nrm = scal[129];
  float n = rng_val((unsigned)s);
  float v_reg = __fdiv_rn(n, nrm);
  float vp_reg = 0.0f;
  lds_v[tid] = v_reg;
  float o0=0.0f,o1=0.0f,o2=0.0f,o3=0.0f;
  for (int m=0;m<MKRY;++m){
    if (m>0) (vbase + (size_t)(m%vmod)*DIM)[s] = v_reg;
    gbar(bar, (unsigned)(baseEpoch+1+m));
    float w;
    if (m==0){
      GetRng g{lds_v, nrm};
      w = matvec_g(s, v_reg, lds_hxz, g);
    } else {
      GetDir g{lds_v, vbase + (size_t)(m%vmod)*DIM};
      w = matvec_g(s, v_reg, lds_hxz, g);
    }
    float alpha = lds_ab[m];
    float bp = (m==0)? 0.0f : lds_ab[64+m-1];
    float beta = fmaxf(lds_ab[64+m], 1e-12f);
    float x;
    {
      #pragma clang fp contract(off)
      x = w - alpha*v_reg;
      x = x - bp*vp_reg;
    }
    float vn = __fdiv_rn(x, beta);
    {
      #pragma clang fp contract(off)
      o0 = o0 + v_reg*lds_ab[128+4*m+0];
      o1 = o1 + v_reg*lds_ab[128+4*m+1];
      o2 = o2 + v_reg*lds_ab[128+4*m+2];
      o3 = o3 + v_reg*lds_ab[128+4*m+3];
    }
    vp_reg = v_reg; v_reg = vn;
    __syncthreads();
    lds_v[tid] = vn;
  }
  *(float4*)(out + 4 + 4*(size_t)s) = make_float4(o0,o1,o2,o3);
}

// tql2 (EISPACK) f64; all 64 lanes redundantly run the scalar chain in registers,
// each applies rotations to its own Z row fused in-loop.
// R5: hypot -> sqrt(fma(..)); two divides -> one reciprocal (values are O(1-10),
// no overflow/underflow risk; perturbs U at ~1e-15, far below the 0.157 threshold).
__global__ void k_eigh(float* __restrict__ scal, float* __restrict__ out){
  __shared__ double dd[64], ee[64];
  __shared__ double Z[64][65];
  int t = threadIdx.x;
  dd[t] = (double)scal[t];
  ee[t] = (t<63)? (double)scal[64+t] : 0.0;
  for (int j=0;j<64;++j) Z[t][j] = (t==j)?1.0:0.0;
  __syncthreads();
  for (int l=0;l<64;++l){
    for (int iter=0; iter<80; ++iter){
      int m=l;
      while (m<63){
        double s2 = fabs(dd[m])+fabs(dd[m+1]);
        if (fabs(ee[m]) <= 2.220446049250313e-16 * s2) break;
        ++m;
      }
      if (m==l) break;
      double g = (dd[l+1]-dd[l])/(2.0*ee[l]);
      double r = sqrt(fma(g,g,1.0));
      g = dd[m]-dd[l] + ee[l]/(g + copysign(r,g));
      double s=1.0, c=1.0, p=0.0;
      int i = m-1;
      bool brk=false;
      for (; i>=l; --i){
        double f = s*ee[i], b = c*ee[i];
        r = sqrt(fma(f,f,g*g));
        if (t==0) ee[i+1] = r;
        if (r==0.0){
          if (t==0){ dd[i+1] -= p; ee[m]=0.0; }
          brk=true;
          break;
        }
        double inv = 1.0/r;
        s = f*inv; c = g*inv;
        g = dd[i+1]-p;
        double r2 = (dd[i]-g)*s + 2.0*c*b;
        p = s*r2;
        if (t==0) dd[i+1] = g+p;
        g = c*r2 - b;
        // apply rotation i to own row
        double zf = Z[t][i+1], zi = Z[t][i];
        Z[t][i+1] = s*zi + c*zf;
        Z[t][i]   = c*zi - s*zf;
      }
      if (!brk && t==0){ dd[l] -= p; ee[l] = g; ee[m] = 0.0; }
      __syncthreads();
    }
  }
  // ascending selection sort, permute columns
  for (int k=0;k<63;++k){
    int jm=k;
    for (int j=k+1;j<64;++j) if (dd[j]<dd[jm]) jm=j;
    __syncthreads();
    if (jm!=k){
      if (t==0){ double tmp=dd[k]; dd[k]=dd[jm]; dd[jm]=tmp; }
      double tz=Z[t][k]; Z[t][k]=Z[t][jm]; Z[t][jm]=tz;
    }
    __syncthreads();
  }
  if (t<4) out[t] = (float)dd[t];
  for (int k=0;k<4;++k) scal[192 + t*4 + k] = (float)Z[t][k];
}

extern "C" void kernel_launch(void* const* d_in, const int* in_sizes, int n_in,
                              void* d_out, int out_size, void* d_ws, size_t ws_size,
                              hipStream_t stream){
  (void)in_sizes; (void)n_in; (void)out_size;
  const float* B0   = (const float*)d_in[0];
  const float* Bext = (const float*)d_in[1];
  const float* phi  = (const float*)d_in[2];
  float* out = (float*)d_out;

  size_t need_big = ((size_t)(MKRY+2)*DIM)*4 + 1024*8 + 512*4 + 256;
  int vmod; bool big;
  if (ws_size >= need_big + (1u<<20)) { vmod = MKRY; big = true; }
  else                               { vmod = 3;    big = false; }

  float* vbase = (float*)d_ws;
  float* wring = vbase + (size_t)vmod*DIM;
  double* part = (double*)(wring + 2*(size_t)DIM);
  float* scal  = (float*)(part + 1024);
  unsigned* bar = (unsigned*)(scal + 512);

  hipLaunchKernelGGL(k_init, dim3(1), dim3(1), 0, stream, bar);
  {
    void* args[] = { (void*)&B0, (void*)&Bext, (void*)&phi,
                     (void*)&vbase, (void*)&vmod, (void*)&wring,
                     (void*)&part, (void*)&scal, (void*)&bar };
    (void)hipLaunchCooperativeKernel((const void*)k_pass1, dim3(NBLOCK), dim3(TPB), args, 0, stream);
  }
  hipLaunchKernelGGL(k_eigh, dim3(1), dim3(64), 0, stream, scal, out);
  if (big){
    hipLaunchKernelGGL(k_pass2s, dim3(DIM/256), dim3(256), 0, stream, vbase, scal, out);
  } else {
    int baseEpoch = 66;
    void* args[] = { (void*)&vbase, (void*)&vmod, (void*)&scal,
                     (void*)&out, (void*)&bar, (void*)&baseEpoch };
    (void)hipLaunchCooperativeKernel((const void*)k_pass2c, dim3(NBLOCK), dim3(TPB), args, 0, stream);
  }
}

// Round 6
// 2895.354 us; speedup vs baseline: 2.8611x; 1.1505x over previous
//
#include <hip/hip_runtime.h>
#include <stdint.h>

#define L 18
#define DIM (1 << L)
#define MKRY 64
#define NBLOCK 256
#define TPB 1024

// ---------------- threefry2x32 (JAX) ----------------
__device__ __forceinline__ uint32_t rotl32(uint32_t v, int r){ return (v<<r)|(v>>(32-r)); }

__device__ __forceinline__ void threefry2x32(uint32_t k0, uint32_t k1, uint32_t x0, uint32_t x1,
                                             uint32_t& o0, uint32_t& o1) {
  uint32_t k2 = k0 ^ k1 ^ 0x1BD11BDAu;
  x0 += k0; x1 += k1;
  x0+=x1; x1=rotl32(x1,13); x1^=x0;
  x0+=x1; x1=rotl32(x1,15); x1^=x0;
  x0+=x1; x1=rotl32(x1,26); x1^=x0;
  x0+=x1; x1=rotl32(x1,6);  x1^=x0;
  x0+=k1; x1+=k2+1u;
  x0+=x1; x1=rotl32(x1,17); x1^=x0;
  x0+=x1; x1=rotl32(x1,29); x1^=x0;
  x0+=x1; x1=rotl32(x1,16); x1^=x0;
  x0+=x1; x1=rotl32(x1,24); x1^=x0;
  x0+=k2; x1+=k0+2u;
  x0+=x1; x1=rotl32(x1,13); x1^=x0;
  x0+=x1; x1=rotl32(x1,15); x1^=x0;
  x0+=x1; x1=rotl32(x1,26); x1^=x0;
  x0+=x1; x1=rotl32(x1,6);  x1^=x0;
  x0+=k0; x1+=k1+3u;
  x0+=x1; x1=rotl32(x1,17); x1^=x0;
  x0+=x1; x1=rotl32(x1,29); x1^=x0;
  x0+=x1; x1=rotl32(x1,16); x1^=x0;
  x0+=x1; x1=rotl32(x1,24); x1^=x0;
  x0+=k1; x1+=k2+4u;
  x0+=x1; x1=rotl32(x1,13); x1^=x0;
  x0+=x1; x1=rotl32(x1,15); x1^=x0;
  x0+=x1; x1=rotl32(x1,26); x1^=x0;
  x0+=x1; x1=rotl32(x1,6);  x1^=x0;
  x0+=k2; x1+=k0+5u;
  o0=x0; o1=x1;
}

__device__ float jax_erfinv(float x){
  #pragma clang fp contract(off)
  float w = -log1pf(-x*x);
  float p;
  if (w < 5.0f) {
    w = w - 2.5f;
    p = 2.81022636e-08f;
    p = 3.43273939e-07f + p*w;
    p = -3.5233877e-06f + p*w;
    p = -4.39150654e-06f + p*w;
    p = 0.00021858087f + p*w;
    p = -0.00125372503f + p*w;
    p = -0.00417768164f + p*w;
    p = 0.246640727f + p*w;
    p = 1.50140941f + p*w;
  } else {
    w = sqrtf(w) - 3.0f;
    p = -0.000200214257f;
    p = 0.000100950558f + p*w;
    p = 0.00134934322f + p*w;
    p = -0.00367342844f + p*w;
    p = 0.00573950773f + p*w;
    p = -0.0076224613f + p*w;
    p = 0.00943887047f + p*w;
    p = 1.00167406f + p*w;
    p = 2.83297682f + p*w;
  }
  return p*x;
}

__device__ __forceinline__ float rng_val(unsigned i){
  #pragma clang fp contract(off)
  uint32_t o0,o1; threefry2x32(0u,42u,0u,i,o0,o1);
  uint32_t bits = o0 ^ o1;
  float f = __uint_as_float((bits >> 9) | 0x3f800000u) - 1.0f;
  const float lo = -0.99999994f;
  float u = f*2.0f;
  u = u + lo;
  u = fmaxf(lo, u);
  return 1.41421354f * jax_erfinv(u);
}

// Deterministic block reduce of two doubles; result broadcast to all threads.
__device__ __forceinline__ double2 blockReduce2(double a, double b){
  __shared__ double sa[16], sb[16], res[2];
  int lane = threadIdx.x & 63, wid = threadIdx.x >> 6;
  #pragma unroll
  for (int off=32; off; off>>=1){ a += __shfl_down(a,off,64); b += __shfl_down(b,off,64); }
  if (lane==0){ sa[wid]=a; sb[wid]=b; }
  __syncthreads();
  if (wid==0){
    double xa = (lane<16)? sa[lane] : 0.0;
    double xb = (lane<16)? sb[lane] : 0.0;
    #pragma unroll
    for (int off=8; off; off>>=1){ xa += __shfl_down(xa,off,64); xb += __shfl_down(xb,off,64); }
    if (lane==0){ res[0]=xa; res[1]=xb; }
  }
  __syncthreads();
  double2 r; r.x=res[0]; r.y=res[1];
  return r;
}

// ---------------- custom grid barrier (requires co-resident launch) ----------------
__device__ __forceinline__ void gbar(unsigned* bar, unsigned epoch){
  __syncthreads();
  if (threadIdx.x==0){
    unsigned prev = __hip_atomic_fetch_add(&bar[0], 1u, __ATOMIC_ACQ_REL, __HIP_MEMORY_SCOPE_AGENT);
    if (prev == NBLOCK-1u){
      __hip_atomic_store(&bar[0], 0u, __ATOMIC_RELAXED, __HIP_MEMORY_SCOPE_AGENT);
      __hip_atomic_fetch_add(&bar[1], 1u, __ATOMIC_RELEASE, __HIP_MEMORY_SCOPE_AGENT);
    } else {
      unsigned g; unsigned guard=0;
      do {
        g = __hip_atomic_load(&bar[1], __ATOMIC_RELAXED, __HIP_MEMORY_SCOPE_AGENT);
        if (g >= epoch) break;
        __builtin_amdgcn_s_sleep(1);
      } while (++guard < (1u<<20));
      (void)__hip_atomic_load(&bar[1], __ATOMIC_ACQUIRE, __HIP_MEMORY_SCOPE_AGENT);
    }
  }
  __syncthreads();
}

// ---------------- matrix-free H, neighbor access via functor ----------------
struct GetDir {
  const float* lds; const float* arr;
  __device__ __forceinline__ float operator()(unsigned nb, bool intra) const {
    return intra ? lds[nb & 1023u] : arr[nb];
  }
};
struct GetRec {  // reconstruct v_m[nb] = ((w-a*va)-bpp*vb)/bden  (bit-identical to owner's path)
  const float* lds; const float *wp, *va, *vb; float a_p, b_pp, bden;
  __device__ __forceinline__ float operator()(unsigned nb, bool intra) const {
    #pragma clang fp contract(off)
    if (intra) return lds[nb & 1023u];
    float x = wp[nb] - a_p*va[nb];
    x = x - b_pp*vb[nb];
    return __fdiv_rn(x, bden);
  }
};
struct GetRng {  // recompute v0[nb] = rng(nb)/nrm
  const float* lds; float nrm;
  __device__ __forceinline__ float operator()(unsigned nb, bool intra) const {
    if (intra) return lds[nb & 1023u];
    return __fdiv_rn(rng_val(nb), nrm);
  }
};

template<class G>
__device__ __forceinline__ float matvec_g(int s, float vs, const float* hxz, const G& g){
  #pragma clang fp contract(off)
  float acc = 0.0f;
  // bonds i=0..16, site i = bit (17-i), site i+1 = bit (16-i)
  #pragma unroll
  for (int i=0;i<L-1;++i){
    const int q = L-2-i;
    const unsigned msk = 3u<<q;
    const bool intra = (msk < 1024u);
    unsigned b2 = ((unsigned)s >> q) & 3u;
    if (b2==0u || b2==3u) { acc = acc + 0.25f*vs; }
    else if (b2==1u) { float t = -0.25f*vs; t = t + 0.5f*g((unsigned)s^msk, intra); acc = acc + t; }
    else             { float t = 0.5f*g((unsigned)s^msk, intra); t = t + (-0.25f)*vs; acc = acc + t; }
  }
  // fields i=0..17, site i = bit (17-i)
  #pragma unroll
  for (int i=0;i<L;++i){
    const int p = L-1-i;
    const unsigned msk = 1u<<p;
    const bool intra = (msk < 1024u);
    float hx = hxz[i], hz = hxz[18+i];
    float t;
    if ((unsigned)s & msk) { t = hx*g((unsigned)s^msk, intra); t = t + (-hz)*vs; }
    else                   { t = hz*vs; t = t + hx*g((unsigned)s^msk, intra); }
    acc = acc + t;
  }
  return acc;
}

// scal layout (floats): [0..63] alphas | [64..127] betas | [129] nrm |
// [130..147] hx | [148..165] hz | [192..447] U (64x4)

__global__ void k_init(unsigned* bar){ bar[0]=0u; bar[1]=0u; }

__global__ void __launch_bounds__(TPB) k_pass1(const float* __restrict__ B0,
        const float* __restrict__ Bext, const float* __restrict__ phi,
        float* __restrict__ vbase, int vmod, float* __restrict__ wring,
        double* __restrict__ part, float* scal, unsigned* bar){
  __shared__ float lds_v[TPB];
  __shared__ float lds_hxz[36];
  const int tid = threadIdx.x, bid = blockIdx.x;
  const int s = bid*TPB + tid;

  if (bid==0 && tid < L){
    #pragma clang fp contract(off)
    float b0 = B0[0], be = Bext[0];
    double ph = (double)phi[tid];
    float Bx = b0*(float)sin(ph);
    float Bz = b0*(float)cos(ph);
    Bz = Bz + be;
    scal[130+tid] = 0.5f*Bx;
    scal[148+tid] = 0.5f*Bz;
  }

  float n = rng_val((unsigned)s);
  {
    double2 pr = blockReduce2((double)n*(double)n, 0.0);
    double* pb = part + 512;  // RNG uses buf1
    if (tid==0){ pb[2*bid]=pr.x; pb[2*bid+1]=pr.y; }
  }
  gbar(bar, 1);

  if (tid < 36) lds_hxz[tid] = scal[130+tid];

  float v_reg;
  float nrm;
  {
    double pa=0.0, pbv=0.0;
    const double* pb = part + 512;
    if (tid<NBLOCK){ pa=pb[2*tid]; pbv=pb[2*tid+1]; }
    double2 t = blockReduce2(pa, pbv);
    nrm = (float)sqrt(t.x);
    v_reg = __fdiv_rn(n, nrm);
    vbase[s] = v_reg;          // slot 0 = v_0
    if (s==0) scal[129] = nrm;
    lds_v[tid] = v_reg;
  }
  float vp_reg = 0.0f, a_p = 0.0f, b_p = 0.0f, b_pp = 0.0f;
  gbar(bar, 2);

  for (int m=0; m<MKRY; ++m){
    __syncthreads();   // lds_v (and lds_hxz) ready
    float w;
    if (m==0){
      GetDir g{lds_v, vbase};
      w = matvec_g(s, v_reg, lds_hxz, g);
    } else {
      const float* va = vbase + (size_t)((m-1)%vmod)*DIM;
      const float* vb = vbase + (size_t)((m+vmod-2)%vmod)*DIM;  // m==1: dummy (x b_pp=0)
      const float* wp = wring + (size_t)((m-1)&1)*DIM;
      GetRec g{lds_v, wp, va, vb, a_p, b_pp, fmaxf(b_p, 1e-12f)};
      w = matvec_g(s, v_reg, lds_hxz, g);
    }
    wring[(size_t)(m&1)*DIM + s] = w;
    if (m>0) (vbase + (size_t)(m%vmod)*DIM)[s] = v_reg;

    double2 p2 = blockReduce2((double)v_reg*(double)w, (double)w*(double)w);
    double* pb = part + (size_t)(m&1)*512;
    if (tid==0){ pb[2*bid]=p2.x; pb[2*bid+1]=p2.y; }
    gbar(bar, 3+(unsigned)m);

    double xa=0.0, xb=0.0;
    if (tid<NBLOCK){ xa=pb[2*tid]; xb=pb[2*tid+1]; }
    double2 tt = blockReduce2(xa, xb);
    float alpha = (float)tt.x;
    double b2d = tt.y - tt.x*tt.x - (double)b_p*(double)b_p;
    float beta = (float)sqrt(fmax(b2d, 0.0));

    float x;
    {
      #pragma clang fp contract(off)
      x = w - alpha*v_reg;
      x = x - b_p*vp_reg;
    }
    float vn = __fdiv_rn(x, fmaxf(beta, 1e-12f));
    if (s==0){ scal[m]=alpha; scal[64+m]=beta; }
    b_pp=b_p; b_p=beta; a_p=alpha; vp_reg=v_reg; v_reg=vn;
    lds_v[tid]=vn;
  }
}

// big-ws: V fully stored, pass2 is a trivial accumulate
__global__ void __launch_bounds__(256) k_pass2s(const float* __restrict__ vbase,
        const float* __restrict__ scal, float* __restrict__ out){
  __shared__ float U[256];
  int tid = threadIdx.x;
  int s = blockIdx.x*256 + tid;
  U[tid] = scal[192+tid];
  __syncthreads();
  {
    #pragma clang fp contract(off)
    float o0=0.0f,o1=0.0f,o2=0.0f,o3=0.0f;
    for (int m=0;m<MKRY;++m){
      float vm = vbase[(size_t)m*DIM + s];
      o0 = o0 + vm*U[4*m+0];
      o1 = o1 + vm*U[4*m+1];
      o2 = o2 + vm*U[4*m+2];
      o3 = o3 + vm*U[4*m+3];
    }
    *(float4*)(out + 4 + 4*(size_t)s) = make_float4(o0,o1,o2,o3);
  }
}

// small-ws: cooperative pass2, direct gather (alphas/betas known)
__global__ void __launch_bounds__(TPB) k_pass2c(float* __restrict__ vbase, int vmod,
        const float* __restrict__ scal, float* __restrict__ out,
        unsigned* bar, int baseEpoch){
  __shared__ float lds_v[TPB];
  __shared__ float lds_hxz[36];
  __shared__ float lds_ab[384];  // [0..127] alphas/betas, [128..383] U
  const int tid = threadIdx.x, bid = blockIdx.x;
  const int s = bid*TPB + tid;
  if (tid < 36) lds_hxz[tid] = scal[130+tid];
  if (tid < 128) lds_ab[tid] = scal[tid];
  if (tid >= 128 && tid < 384) lds_ab[tid] = scal[192 + (tid-128)];
  float nrm = scal[129];
  float n = rng_val((unsigned)s);
  float v_reg = __fdiv_rn(n, nrm);
  float vp_reg = 0.0f;
  lds_v[tid] = v_reg;
  float o0=0.0f,o1=0.0f,o2=0.0f,o3=0.0f;
  for (int m=0;m<MKRY;++m){
    if (m>0) (vbase + (size_t)(m%vmod)*DIM)[s] = v_reg;
    gbar(bar, (unsigned)(baseEpoch+1+m));
    float w;
    if (m==0){
      GetRng g{lds_v, nrm};
      w = matvec_g(s, v_reg, lds_hxz, g);
    } else {
      GetDir g{lds_v, vbase + (size_t)(m%vmod)*DIM};
      w = matvec_g(s, v_reg, lds_hxz, g);
    }
    float alpha = lds_ab[m];
    float bp = (m==0)? 0.0f : lds_ab[64+m-1];
    float beta = fmaxf(lds_ab[64+m], 1e-12f);
    float x;
    {
      #pragma clang fp contract(off)
      x = w - alpha*v_reg;
      x = x - bp*vp_reg;
    }
    float vn = __fdiv_rn(x, beta);
    {
      #pragma clang fp contract(off)
      o0 = o0 + v_reg*lds_ab[128+4*m+0];
      o1 = o1 + v_reg*lds_ab[128+4*m+1];
      o2 = o2 + v_reg*lds_ab[128+4*m+2];
      o3 = o3 + v_reg*lds_ab[128+4*m+3];
    }
    vp_reg = v_reg; v_reg = vn;
    __syncthreads();
    lds_v[tid] = vn;
  }
  *(float4*)(out + 4 + 4*(size_t)s) = make_float4(o0,o1,o2,o3);
}

// tql2 (EISPACK) f64, restructured for latency:
//  - ballot-parallel deflation scan
//  - register-carried scalar chain (no LDS on the serial path), rsqrt fusion
//  - Z rotation application split into a separate per-lane carry loop
//  - shfl-based selection sort (same first-min-index semantics)
// FP order of the rotation recurrence and Z updates is unchanged.
__global__ void k_eigh(float* __restrict__ scal, float* __restrict__ out){
  __shared__ double dd[64], ee[64], ss[64], cc[64];
  __shared__ double Z[64][65];
  int t = threadIdx.x;
  dd[t] = (double)scal[t];
  ee[t] = (t<63)? (double)scal[64+t] : 0.0;
  for (int j=0;j<64;++j) Z[t][j] = (t==j)?1.0:0.0;
  __syncthreads();
  for (int l=0;l<64;++l){
    for (int iter=0; iter<80; ++iter){
      // ---- parallel deflation scan: first m in [l,63) with |ee[m]| small, else 63
      double dt  = dd[t];
      double dt1 = (t<63)? dd[t+1] : 0.0;
      double et  = ee[t];
      bool cond = (t>=l) && (t<63) &&
                  (fabs(et) <= 2.220446049250313e-16 * (fabs(dt)+fabs(dt1)));
      unsigned long long bm = __ballot(cond) | (1ull<<63);
      int m = __builtin_ctzll(bm);
      if (m==l) break;
      // ---- shift (once per sweep)
      double g = (dd[l+1]-dd[l])/(2.0*ee[l]);
      double r = sqrt(fma(g,g,1.0));
      g = dd[m]-dd[l] + ee[l]/(g + copysign(r,g));
      double s=1.0, c=1.0, p=0.0;
      // ---- scalar rotation chain, register-carried inputs
      int stop = l;
      {
        double ee_i  = ee[m-1];
        double dd_i  = dd[m-1];
        double dd_i1 = dd[m];
        for (int i=m-1; i>=l; --i){
          double ee_n=0.0, dd_n=0.0;
          if (i>l){ ee_n = ee[i-1]; dd_n = dd[i-1]; }  // prefetch next (off-chain)
          double f = s*ee_i, b = c*ee_i;
          double h = fma(f,f,g*g);
          if (h==0.0){
            if (t==0){ dd[i+1] = dd_i1 - p; ee[m]=0.0; }
            stop = i+1;
            break;
          }
          double inv = rsqrt(h);
          s = f*inv; c = g*inv;
          g = dd_i1 - p;
          double r2 = (dd_i - g)*s + 2.0*c*b;
          p = s*r2;
          double ddw = g + p;
          g = c*r2 - b;
          if (t==0){ ee[i+1] = h*inv; dd[i+1] = ddw; ss[i]=s; cc[i]=c; }
          dd_i1 = dd_i; ee_i = ee_n; dd_i = dd_n;
          if (i==l){
            if (t==0){ dd[l] = dd[l] - p; ee[l] = g; ee[m] = 0.0; }
          }
        }
      }
      __syncthreads();   // ss/cc/dd/ee visible
      // ---- apply rotations to own Z row (carry pattern; FP-identical to fused)
      int top = m-1;
      if (top >= stop){
        double zhi = Z[t][top+1];
        for (int i=top; i>=stop; --i){
          double zlo = Z[t][i];
          double sI = ss[i], cI = cc[i];
          Z[t][i+1] = sI*zlo + cI*zhi;
          zhi = cI*zlo - sI*zhi;
        }
        Z[t][stop] = zhi;
      }
      __syncthreads();
    }
  }
  // ---- shfl-based ascending selection sort (first-min-index, as before)
  double dv = dd[t];
  for (int k=0;k<63;++k){
    double mv = (t>=k)? dv : 1.0e300;
    int mi = t;
    #pragma unroll
    for (int off=32; off; off>>=1){
      double ov = __shfl_down(mv, off, 64);
      int    oi = __shfl_down(mi, off, 64);
      if (ov < mv || (ov==mv && oi<mi)){ mv=ov; mi=oi; }
    }
    int jm = __shfl(mi, 0, 64);
    if (jm!=k){
      int src = (t==k)? jm : ((t==jm)? k : t);
      dv = __shfl(dv, src, 64);
      double tz=Z[t][k]; Z[t][k]=Z[t][jm]; Z[t][jm]=tz;
    }
  }
  if (t<4) out[t] = (float)dv;
  for (int k=0;k<4;++k) scal[192 + t*4 + k] = (float)Z[t][k];
}

extern "C" void kernel_launch(void* const* d_in, const int* in_sizes, int n_in,
                              void* d_out, int out_size, void* d_ws, size_t ws_size,
                              hipStream_t stream){
  (void)in_sizes; (void)n_in; (void)out_size;
  const float* B0   = (const float*)d_in[0];
  const float* Bext = (const float*)d_in[1];
  const float* phi  = (const float*)d_in[2];
  float* out = (float*)d_out;

  size_t need_big = ((size_t)(MKRY+2)*DIM)*4 + 1024*8 + 512*4 + 256;
  int vmod; bool big;
  if (ws_size >= need_big + (1u<<20)) { vmod = MKRY; big = true; }
  else                               { vmod = 3;    big = false; }

  float* vbase = (float*)d_ws;
  float* wring = vbase + (size_t)vmod*DIM;
  double* part = (double*)(wring + 2*(size_t)DIM);
  float* scal  = (float*)(part + 1024);
  unsigned* bar = (unsigned*)(scal + 512);

  hipLaunchKernelGGL(k_init, dim3(1), dim3(1), 0, stream, bar);
  {
    void* args[] = { (void*)&B0, (void*)&Bext, (void*)&phi,
                     (void*)&vbase, (void*)&vmod, (void*)&wring,
                     (void*)&part, (void*)&scal, (void*)&bar };
    (void)hipLaunchCooperativeKernel((const void*)k_pass1, dim3(NBLOCK), dim3(TPB), args, 0, stream);
  }
  hipLaunchKernelGGL(k_eigh, dim3(1), dim3(64), 0, stream, scal, out);
  if (big){
    hipLaunchKernelGGL(k_pass2s, dim3(DIM/256), dim3(256), 0, stream, vbase, scal, out);
  } else {
    int baseEpoch = 66;
    void* args[] = { (void*)&vbase, (void*)&vmod, (void*)&scal,
                     (void*)&out, (void*)&bar, (void*)&baseEpoch };
    (void)hipLaunchCooperativeKernel((const void*)k_pass2c, dim3(NBLOCK), dim3(TPB), args, 0, stream);
  }
}